// Round 3
// baseline (158.810 us; speedup 1.0000x reference)
//
#include <hip/hip_runtime.h>
#include <cstdint>
#include <cstddef>

namespace {
constexpr int kN    = 65536;     // nodes
constexpr int kF    = 256;       // feats
constexpr int kC    = 64;        // pools per graph
constexpr int kNPG  = 1024;      // nodes per graph
constexpr int kB    = 64;        // graphs
constexpr int kE    = 2097152;   // edges
constexpr int kK    = kB * kC;   // 4096 global clusters

// d_out offsets (in floats)
constexpr size_t OFF_OUT  = 0;                           // [4096,256]
constexpr size_t OFF_EIDX = (size_t)kK * kF;             // 1048576  [2,262144]
constexpr size_t OFF_ADJ  = OFF_EIDX + 2ull*kB*kC*kC;    // 1572864  [262144]
constexpr size_t OFF_LL   = OFF_ADJ + (size_t)kB*kC*kC;  // 1835008
constexpr size_t OFF_Z    = OFF_LL + 1;                  // 1835009
constexpr size_t OFF_BOUT = OFF_Z + 1;                   // 1835010  [4096]
constexpr size_t OFF_BPTR = OFF_BOUT + kK;               // 1839106  [65]

// ws offsets (bytes)
constexpr size_t WS_C    = 0;        // int[65536]
constexpr size_t WS_V    = 262144;   // float[65536]
constexpr size_t WS_VS2  = 524288;   // float[4096]
constexpr size_t WS_A2   = 540672;   // float[256]
constexpr size_t WS_PADJ = 544768;   // float[256*4096] = 4 MiB
} // namespace

// ---------------------------------------------------------------- constants
__global__ __launch_bounds__(256) void k_const(float* __restrict__ out)
{
    const int i = blockIdx.x * 256 + threadIdx.x;
    constexpr int E2 = 2 * kB * kC * kC;      // 524288
    if (i < E2) {
        const int half = i >= kB*kC*kC;
        const int idx  = half ? i - kB*kC*kC : i;
        const int bb = idx >> 12, rem = idx & 4095;
        const int val = half ? bb*kC + (rem & 63) : bb*kC + (rem >> 6);
        out[OFF_EIDX + i] = (float)val;
    } else if (i < E2 + kK) {
        const int j = i - E2;
        out[OFF_BOUT + j] = (float)(j >> 6);
    } else if (i < E2 + kK + kB + 1) {
        const int j = i - (E2 + kK);
        out[OFF_BPTR + j] = (float)(j * kC);
    }
}

// ------------------------------------------------- K1: logits -> c, v
// GEMM M=65536 N=64 K=256, block = 256 thr, BM=128 nodes, reg tile 4x8.
__global__ __launch_bounds__(256) void k_logits(
    const float* __restrict__ x, const float* __restrict__ Wm,
    const float* __restrict__ bv, int* __restrict__ carr,
    float* __restrict__ varr)
{
    constexpr int BM = 128, KCc = 32, BMP = 132;  // pad -> conflict-free b128
    __shared__ float xs[KCc][BMP];   // transposed tile  [k][node]
    __shared__ float wsd[KCc][kC];
    const int tid = threadIdx.x;
    const int tx  = tid & 7;    // col group: cols tx*8 .. tx*8+7
    const int ty  = tid >> 3;   // row group: rows ty*4 .. ty*4+3
    const int nbase = blockIdx.x * BM;

    float acc[4][8];
#pragma unroll
    for (int j = 0; j < 8; ++j) {
        const float bb = bv[tx*8 + j];
#pragma unroll
        for (int i = 0; i < 4; ++i) acc[i][j] = bb;
    }

    for (int kc = 0; kc < kF; kc += KCc) {
        __syncthreads();
#pragma unroll
        for (int r = 0; r < 4; ++r) {
            const int idx  = tid + 256*r;     // 0..1023 float4 slots
            const int node = idx >> 3;
            const int k4   = (idx & 7) << 2;
            const float4 g = *reinterpret_cast<const float4*>(
                x + (size_t)(nbase + node)*kF + kc + k4);
            xs[k4+0][node] = g.x; xs[k4+1][node] = g.y;
            xs[k4+2][node] = g.z; xs[k4+3][node] = g.w;
        }
#pragma unroll
        for (int r = 0; r < 8; ++r) {
            const int idx = tid + 256*r;      // 0..2047
            wsd[idx >> 6][idx & 63] =
                Wm[(size_t)(kc + (idx >> 6))*kC + (idx & 63)];
        }
        __syncthreads();
#pragma unroll
        for (int kk = 0; kk < KCc; ++kk) {
            const float4 xa = *reinterpret_cast<const float4*>(&xs[kk][ty*4]);
            const float4 wa = *reinterpret_cast<const float4*>(&wsd[kk][tx*8]);
            const float4 wb = *reinterpret_cast<const float4*>(&wsd[kk][tx*8+4]);
            const float xv[4] = {xa.x, xa.y, xa.z, xa.w};
            const float wv[8] = {wa.x, wa.y, wa.z, wa.w,
                                 wb.x, wb.y, wb.z, wb.w};
#pragma unroll
            for (int i = 0; i < 4; ++i)
#pragma unroll
                for (int j = 0; j < 8; ++j)
                    acc[i][j] = fmaf(xv[i], wv[j], acc[i][j]);
        }
    }

    // per-node softmax-argmax over 64 cols spread across 8 lanes x 8 regs
#pragma unroll
    for (int i = 0; i < 4; ++i) {
        float m = acc[i][0];
        int   ci = tx*8;
#pragma unroll
        for (int j = 1; j < 8; ++j)
            if (acc[i][j] > m) { m = acc[i][j]; ci = tx*8 + j; }
#pragma unroll
        for (int off = 1; off < 8; off <<= 1) {
            const float om = __shfl_xor(m, off);
            const int   oc = __shfl_xor(ci, off);
            if (om > m || (om == m && oc < ci)) { m = om; ci = oc; }
        }
        float s = 0.f;
#pragma unroll
        for (int j = 0; j < 8; ++j) s += expf(acc[i][j] - m);
#pragma unroll
        for (int off = 1; off < 8; off <<= 1) s += __shfl_xor(s, off);
        if (tx == 0) {
            const float p = 1.0f / s;
            const int n = nbase + ty*4 + i;
            carr[n] = ci;
            varr[n] = (1.0f - p) + p;   // straight-through forward value
        }
    }
}

// ------------------------------------- K2: out = S^T x  (+ vs2), atomic-free
// block = (graph, feat-quarter); exclusive ownership of its 64x64 out slab.
// 1024 threads (16 waves/CU) to hide global-load + LDS-atomic latency.
__global__ __launch_bounds__(1024) void k_pool_x(
    const float* __restrict__ x, const int* __restrict__ carr,
    const float* __restrict__ varr, float* __restrict__ out,
    float* __restrict__ vs2)
{
    __shared__ float acc[kC][65];
    __shared__ float acc2[kC];
    const int tid = threadIdx.x;
    const int g   = blockIdx.x >> 2;
    const int fq  = blockIdx.x & 3;
    for (int i = tid; i < kC*65; i += 1024) (&acc[0][0])[i] = 0.f;
    if (tid < kC) acc2[tid] = 0.f;
    __syncthreads();

    const int q   = tid & 15;    // feat lane (16 per node, float4 each)
    const int sub = tid >> 4;    // node sub-index (0..63)
    const int fbase = fq*64 + q*4;
    for (int it = 0; it < 16; it += 2) {
        float4 xv[2]; int cn[2]; float vn[2];
#pragma unroll
        for (int u = 0; u < 2; ++u) {
            const int n = g*kNPG + (it+u)*64 + sub;
            xv[u] = *reinterpret_cast<const float4*>(x + (size_t)n*kF + fbase);
            cn[u] = carr[n];
            vn[u] = varr[n];
        }
#pragma unroll
        for (int u = 0; u < 2; ++u) {
            float* row = acc[cn[u]];
            atomicAdd(&row[q*4+0], vn[u]*xv[u].x);
            atomicAdd(&row[q*4+1], vn[u]*xv[u].y);
            atomicAdd(&row[q*4+2], vn[u]*xv[u].z);
            atomicAdd(&row[q*4+3], vn[u]*xv[u].w);
        }
    }
    // vs2: one node per thread, only in fq==0 blocks
    if (fq == 0) {
        const int n = g*kNPG + tid;
        const float v = varr[n];
        atomicAdd(&acc2[carr[n]], v*v);
    }
    __syncthreads();
    // 64x64 slab = 4096 entries = 4 * 1024 threads  (r<4 — NOT 16!)
#pragma unroll
    for (int r = 0; r < 4; ++r) {
        const int lin = r*1024 + tid;
        const int c = lin >> 6, fl = lin & 63;
        out[OFF_OUT + (size_t)(g*kC + c)*kF + fq*64 + fl] = acc[c][fl];
    }
    if (fq == 0 && tid < kC) vs2[g*kC + tid] = acc2[tid];
}

// ------------------------------------- K4: adjacency partials (+ a2 partial)
// 1024 threads (16 waves/CU); 256 blocks = 64 graphs x 4 edge-chunks.
__global__ __launch_bounds__(1024) void k_adj(
    const int* __restrict__ ei, const float* __restrict__ ew,
    const int* __restrict__ carr, const float* __restrict__ varr,
    float* __restrict__ padj, float* __restrict__ a2p)
{
    __shared__ float adj[kC*kC];
    __shared__ float wred[16];
    const int tid = threadIdx.x;
    const int bid = blockIdx.x;             // 256 blocks
    for (int i = tid; i < kC*kC; i += 1024) adj[i] = 0.f;
    __syncthreads();
    const int e0 = bid * 8192;
    float a2l = 0.f;
    for (int it = 0; it < 8; it += 4) {
        int sn[4], dn[4]; float w[4];
#pragma unroll
        for (int u = 0; u < 4; ++u) {
            const int e = e0 + (it+u)*1024 + tid;
            sn[u] = ei[e]; dn[u] = ei[kE + e]; w[u] = ew[e];
        }
        int ci[4], cj[4]; float vv[4];
#pragma unroll
        for (int u = 0; u < 4; ++u) {
            ci[u] = carr[sn[u]]; cj[u] = carr[dn[u]];
            vv[u] = varr[sn[u]] * varr[dn[u]];
        }
#pragma unroll
        for (int u = 0; u < 4; ++u) {
            atomicAdd(&adj[ci[u]*kC + cj[u]], w[u]*vv[u]);
            a2l += w[u]*w[u];
        }
    }
    __syncthreads();
#pragma unroll
    for (int r = 0; r < 4; ++r) {
        const int lin = r*1024 + tid;
        padj[(size_t)bid*4096 + lin] = adj[lin];
    }
#pragma unroll
    for (int off = 32; off > 0; off >>= 1) a2l += __shfl_down(a2l, off);
    if ((tid & 63) == 0) wred[tid >> 6] = a2l;
    __syncthreads();
    if (tid == 0) {
        float s = 0.f;
#pragma unroll
        for (int wv = 0; wv < 16; ++wv) s += wred[wv];
        a2p[bid] = s;
    }
}

// ------------------------------------- K5: merge adjacency partials
__global__ __launch_bounds__(256) void k_adj_merge(
    const float* __restrict__ padj, float* __restrict__ out)
{
    const int id = blockIdx.x*256 + threadIdx.x;   // < 262144
    const int g = id >> 12, idx = id & 4095;
    float s = 0.f;
#pragma unroll
    for (int sp = 0; sp < 4; ++sp) s += padj[(size_t)(g*4 + sp)*4096 + idx];
    out[OFF_ADJ + id] = s;
}

// ------------------------------------- K6: link_loss scalar
__global__ __launch_bounds__(256) void k_final(
    const float* __restrict__ vs2, const float* __restrict__ a2p,
    float* __restrict__ out)
{
    const int tid = threadIdx.x;
    float p2l = 0.f, apl = 0.f;
#pragma unroll
    for (int r = 0; r < 16; ++r) {
        const int k = r*256 + tid;
        const float t = vs2[k];
        p2l += t*t;
        const int g = k >> 6, cc = k & 63;
        apl += out[OFF_ADJ + (size_t)g*4096 + cc*65];   // diagonal entries
    }
    float a2l = a2p[tid];
#pragma unroll
    for (int off = 32; off > 0; off >>= 1) {
        p2l += __shfl_down(p2l, off);
        apl += __shfl_down(apl, off);
        a2l += __shfl_down(a2l, off);
    }
    __shared__ float red[3][4];
    if ((tid & 63) == 0) {
        red[0][tid>>6] = p2l; red[1][tid>>6] = apl; red[2][tid>>6] = a2l;
    }
    __syncthreads();
    if (tid == 0) {
        const float p2 = red[0][0]+red[0][1]+red[0][2]+red[0][3];
        const float ap = red[1][0]+red[1][1]+red[1][2]+red[1][3];
        const float a2 = red[2][0]+red[2][1]+red[2][2]+red[2][3];
        const float val = a2 - 2.0f*ap + p2;
        out[OFF_LL] = sqrtf(fmaxf(val, 0.f)) / (float)kE;
        out[OFF_Z]  = 0.0f;
    }
}

// ----------------------------------------------------------------- launch
extern "C" void kernel_launch(void* const* d_in, const int* in_sizes, int n_in,
                              void* d_out, int out_size, void* d_ws, size_t ws_size,
                              hipStream_t stream)
{
    const float* x  = (const float*)d_in[0];
    const int*   ei = (const int*)d_in[1];
    const float* ew = (const float*)d_in[2];
    // d_in[3] = batch, d_in[4] = batch_ptr: implied by block structure
    const float* Wm = (const float*)d_in[5];
    const float* bv = (const float*)d_in[6];
    float* out = (float*)d_out;
    char*  ws  = (char*)d_ws;
    int*   carr = (int*)(ws + WS_C);
    float* varr = (float*)(ws + WS_V);
    float* vs2  = (float*)(ws + WS_VS2);
    float* a2p  = (float*)(ws + WS_A2);
    float* padj = (float*)(ws + WS_PADJ);

    k_const    <<<2065, 256, 0, stream>>>(out);
    k_logits   <<<512,  256, 0, stream>>>(x, Wm, bv, carr, varr);
    k_pool_x   <<<256, 1024, 0, stream>>>(x, carr, varr, out, vs2);
    k_adj      <<<256, 1024, 0, stream>>>(ei, ew, carr, varr, padj, a2p);
    k_adj_merge<<<1024, 256, 0, stream>>>(padj, out);
    k_final    <<<1,    256, 0, stream>>>(vs2, a2p, out);
}

// Round 4
// 92.009 us; speedup vs baseline: 1.7260x; 1.7260x over previous
//
#include <hip/hip_runtime.h>
#include <cstdint>
#include <cstddef>

namespace {
constexpr int kN    = 65536;     // nodes
constexpr int kF    = 256;       // feats
constexpr int kC    = 64;        // pools per graph
constexpr int kNPG  = 1024;      // nodes per graph
constexpr int kB    = 64;        // graphs
constexpr int kE    = 2097152;   // edges
constexpr int kK    = kB * kC;   // 4096 global clusters

// d_out offsets (in floats)
constexpr size_t OFF_OUT  = 0;                           // [4096,256]
constexpr size_t OFF_EIDX = (size_t)kK * kF;             // 1048576  [2,262144]
constexpr size_t OFF_ADJ  = OFF_EIDX + 2ull*kB*kC*kC;    // 1572864  [262144]
constexpr size_t OFF_LL   = OFF_ADJ + (size_t)kB*kC*kC;  // 1835008
constexpr size_t OFF_Z    = OFF_LL + 1;                  // 1835009
constexpr size_t OFF_BOUT = OFF_Z + 1;                   // 1835010  [4096]
constexpr size_t OFF_BPTR = OFF_BOUT + kK;               // 1839106  [65]

// ws offsets (bytes). NOTE: PERM/START overlap PADJ — lifetimes are
// stream-disjoint (perm/start: written k_sort, read k_pool_x; padj:
// written k_adj afterwards, read k_adj_merge). Total usage unchanged.
constexpr size_t WS_C    = 0;        // int[65536]
constexpr size_t WS_V    = 262144;   // float[65536]
constexpr size_t WS_VS2  = 524288;   // float[4096]
constexpr size_t WS_A2   = 540672;   // float[256]
constexpr size_t WS_PERM = 544768;   // int[65536]   (dead after k_pool_x)
constexpr size_t WS_STRT = 806912;   // int[64*65]   (dead after k_pool_x)
constexpr size_t WS_PADJ = 544768;   // float[256*4096] = 4 MiB (k_adj onward)
} // namespace

// ---------------------------------------------------------------- constants
__global__ __launch_bounds__(256) void k_const(float* __restrict__ out)
{
    const int i = blockIdx.x * 256 + threadIdx.x;
    constexpr int E2 = 2 * kB * kC * kC;      // 524288
    if (i < E2) {
        const int half = i >= kB*kC*kC;
        const int idx  = half ? i - kB*kC*kC : i;
        const int bb = idx >> 12, rem = idx & 4095;
        const int val = half ? bb*kC + (rem & 63) : bb*kC + (rem >> 6);
        out[OFF_EIDX + i] = (float)val;
    } else if (i < E2 + kK) {
        const int j = i - E2;
        out[OFF_BOUT + j] = (float)(j >> 6);
    } else if (i < E2 + kK + kB + 1) {
        const int j = i - (E2 + kK);
        out[OFF_BPTR + j] = (float)(j * kC);
    }
}

// ------------------------------------------------- K1: logits -> c, v
__global__ __launch_bounds__(256) void k_logits(
    const float* __restrict__ x, const float* __restrict__ Wm,
    const float* __restrict__ bv, int* __restrict__ carr,
    float* __restrict__ varr)
{
    constexpr int BM = 128, KCc = 32, BMP = 132;
    __shared__ float xs[KCc][BMP];   // transposed tile  [k][node]
    __shared__ float wsd[KCc][kC];
    const int tid = threadIdx.x;
    const int tx  = tid & 7;
    const int ty  = tid >> 3;
    const int nbase = blockIdx.x * BM;

    float acc[4][8];
#pragma unroll
    for (int j = 0; j < 8; ++j) {
        const float bb = bv[tx*8 + j];
#pragma unroll
        for (int i = 0; i < 4; ++i) acc[i][j] = bb;
    }

    for (int kc = 0; kc < kF; kc += KCc) {
        __syncthreads();
#pragma unroll
        for (int r = 0; r < 4; ++r) {
            const int idx  = tid + 256*r;
            const int node = idx >> 3;
            const int k4   = (idx & 7) << 2;
            const float4 g = *reinterpret_cast<const float4*>(
                x + (size_t)(nbase + node)*kF + kc + k4);
            xs[k4+0][node] = g.x; xs[k4+1][node] = g.y;
            xs[k4+2][node] = g.z; xs[k4+3][node] = g.w;
        }
#pragma unroll
        for (int r = 0; r < 8; ++r) {
            const int idx = tid + 256*r;
            wsd[idx >> 6][idx & 63] =
                Wm[(size_t)(kc + (idx >> 6))*kC + (idx & 63)];
        }
        __syncthreads();
#pragma unroll
        for (int kk = 0; kk < KCc; ++kk) {
            const float4 xa = *reinterpret_cast<const float4*>(&xs[kk][ty*4]);
            const float4 wa = *reinterpret_cast<const float4*>(&wsd[kk][tx*8]);
            const float4 wb = *reinterpret_cast<const float4*>(&wsd[kk][tx*8+4]);
            const float xv[4] = {xa.x, xa.y, xa.z, xa.w};
            const float wv[8] = {wa.x, wa.y, wa.z, wa.w,
                                 wb.x, wb.y, wb.z, wb.w};
#pragma unroll
            for (int i = 0; i < 4; ++i)
#pragma unroll
                for (int j = 0; j < 8; ++j)
                    acc[i][j] = fmaf(xv[i], wv[j], acc[i][j]);
        }
    }

#pragma unroll
    for (int i = 0; i < 4; ++i) {
        float m = acc[i][0];
        int   ci = tx*8;
#pragma unroll
        for (int j = 1; j < 8; ++j)
            if (acc[i][j] > m) { m = acc[i][j]; ci = tx*8 + j; }
#pragma unroll
        for (int off = 1; off < 8; off <<= 1) {
            const float om = __shfl_xor(m, off);
            const int   oc = __shfl_xor(ci, off);
            if (om > m || (om == m && oc < ci)) { m = om; ci = oc; }
        }
        float s = 0.f;
#pragma unroll
        for (int j = 0; j < 8; ++j) s += expf(acc[i][j] - m);
#pragma unroll
        for (int off = 1; off < 8; off <<= 1) s += __shfl_xor(s, off);
        if (tx == 0) {
            const float p = 1.0f / s;
            const int n = nbase + ty*4 + i;
            carr[n] = ci;
            varr[n] = (1.0f - p) + p;
        }
    }
}

// ------------------------------------- K1b: deterministic stable counting sort
// One block per graph. No atomics: match-mask via 6 ballots, per-wave
// histograms, prefix sums. perm = node ids sorted by (cluster, node index).
__global__ __launch_bounds__(1024) void k_sort(
    const int* __restrict__ carr, int* __restrict__ perm,
    int* __restrict__ startc)
{
    __shared__ int hist[16][64];
    __shared__ int startS[65];
    const int g = blockIdx.x;
    const int tid = threadIdx.x;
    const int w = tid >> 6, lane = tid & 63;
    const int c = carr[g*kNPG + tid];
    hist[tid >> 6][tid & 63] = 0;     // 16*64 == 1024: each thread zeroes one
    __syncthreads();
    // lanes with identical cluster within the wave
    unsigned long long mm = ~0ull;
#pragma unroll
    for (int b = 0; b < 6; ++b) {
        const unsigned long long bal = __ballot((c >> b) & 1);
        mm &= ((c >> b) & 1) ? bal : ~bal;
    }
    const unsigned long long ltmask =
        (lane == 0) ? 0ull : (~0ull >> (64 - lane));
    const int rank_in_wave = __popcll(mm & ltmask);
    const int leader = __ffsll((unsigned long long)mm) - 1;
    if (lane == leader) hist[w][c] = __popcll(mm);
    __syncthreads();
    if (w == 0) {
        int tot = 0;
#pragma unroll
        for (int i = 0; i < 16; ++i) tot += hist[i][lane];
        int pre = tot;
#pragma unroll
        for (int off = 1; off < 64; off <<= 1) {
            const int t = __shfl_up(pre, off);
            if (lane >= off) pre += t;
        }
        startS[lane + 1] = pre;
        if (lane == 0) startS[0] = 0;
    }
    __syncthreads();
    int before = startS[c];
    for (int i = 0; i < w; ++i) before += hist[i][c];
    perm[g*kNPG + before + rank_in_wave] = g*kNPG + tid;
    if (tid < 65) startc[g*65 + tid] = startS[tid];
}

// ------------------------------------- K2: out = S^T x (+ vs2) — atomic-FREE
// 512 blocks = (graph, feat-eighth). Wave owns 4 cluster rows; lanes =
// 8 feat-quads x 8 node-slots; register accumulate + shfl reduce.
__global__ __launch_bounds__(1024) void k_pool_x(
    const float* __restrict__ x, const int* __restrict__ perm,
    const int* __restrict__ startc, const float* __restrict__ varr,
    float* __restrict__ out, float* __restrict__ vs2)
{
    const int tid  = threadIdx.x;
    const int g    = blockIdx.x >> 3;
    const int fh   = blockIdx.x & 7;
    const int w    = tid >> 6;
    const int lane = tid & 63;
    const int q    = lane & 7;      // feat quad (float4)
    const int sub  = lane >> 3;     // node slot 0..7
    const int fbase = fh*32 + q*4;
#pragma unroll
    for (int cc = 0; cc < 4; ++cc) {
        const int c = w*4 + cc;
        const int s = startc[g*65 + c];
        const int e = startc[g*65 + c + 1];
        float ax = 0.f, ay = 0.f, az = 0.f, aw = 0.f, v2 = 0.f;
        for (int base = s + sub; base < e; base += 8) {
            const int n = perm[(size_t)g*kNPG + base];
            const float v = varr[n];
            const float4 xv = *reinterpret_cast<const float4*>(
                x + (size_t)n*kF + fbase);
            ax = fmaf(v, xv.x, ax); ay = fmaf(v, xv.y, ay);
            az = fmaf(v, xv.z, az); aw = fmaf(v, xv.w, aw);
            v2 = fmaf(v, v, v2);
        }
        // reduce over node-slots (lane bits 3..5), feat lanes untouched
#pragma unroll
        for (int off = 8; off < 64; off <<= 1) {
            ax += __shfl_xor(ax, off); ay += __shfl_xor(ay, off);
            az += __shfl_xor(az, off); aw += __shfl_xor(aw, off);
            v2 += __shfl_xor(v2, off);
        }
        if (sub == 0) {
            const float4 o = {ax, ay, az, aw};
            *reinterpret_cast<float4*>(
                out + OFF_OUT + (size_t)(g*kC + c)*kF + fbase) = o;
        }
        if (fh == 0 && lane == 0) vs2[g*kC + c] = v2;
    }
}

// ------------------------------------- K4: adjacency partials (+ a2 partial)
// LDS-staged (c, v); 8192 edges/block -> 8192 LDS atomics (8x fewer than old
// k_pool_x per block; acceptable under the per-lane-serialization model).
__global__ __launch_bounds__(1024) void k_adj(
    const int* __restrict__ ei, const float* __restrict__ ew,
    const int* __restrict__ carr, const float* __restrict__ varr,
    float* __restrict__ padj, float* __restrict__ a2p)
{
    __shared__ float adj[kC*kC];   // 16 KB
    __shared__ float vls[kNPG];    // 4 KB
    __shared__ int   cls[kNPG];    // 4 KB
    __shared__ float wred[16];
    const int tid = threadIdx.x;
    const int bid = blockIdx.x;             // 256 blocks = 64 graphs x 4
    const int g   = bid >> 2;
    for (int i = tid; i < kC*kC; i += 1024) adj[i] = 0.f;
    vls[tid] = varr[g*kNPG + tid];
    cls[tid] = carr[g*kNPG + tid];
    __syncthreads();
    const int e0 = bid * 8192;
    float a2l = 0.f;
#pragma unroll
    for (int it = 0; it < 8; ++it) {
        const int e  = e0 + it*1024 + tid;
        const int sn = ei[e]      & (kNPG - 1);
        const int dn = ei[kE + e] & (kNPG - 1);
        const float wv = ew[e];
        a2l += wv * wv;
        atomicAdd(&adj[cls[sn]*kC + cls[dn]], wv * vls[sn] * vls[dn]);
    }
    __syncthreads();
#pragma unroll
    for (int r = 0; r < 4; ++r) {
        const int lin = r*1024 + tid;
        padj[(size_t)bid*4096 + lin] = adj[lin];
    }
#pragma unroll
    for (int off = 32; off > 0; off >>= 1) a2l += __shfl_down(a2l, off);
    if ((tid & 63) == 0) wred[tid >> 6] = a2l;
    __syncthreads();
    if (tid == 0) {
        float s = 0.f;
#pragma unroll
        for (int wv = 0; wv < 16; ++wv) s += wred[wv];
        a2p[bid] = s;
    }
}

// ------------------------------------- K5: merge adjacency partials
__global__ __launch_bounds__(256) void k_adj_merge(
    const float* __restrict__ padj, float* __restrict__ out)
{
    const int id = blockIdx.x*256 + threadIdx.x;   // < 262144
    const int g = id >> 12, idx = id & 4095;
    float s = 0.f;
#pragma unroll
    for (int sp = 0; sp < 4; ++sp) s += padj[(size_t)(g*4 + sp)*4096 + idx];
    out[OFF_ADJ + id] = s;
}

// ------------------------------------- K6: link_loss scalar
__global__ __launch_bounds__(256) void k_final(
    const float* __restrict__ vs2, const float* __restrict__ a2p,
    float* __restrict__ out)
{
    const int tid = threadIdx.x;
    float p2l = 0.f, apl = 0.f;
#pragma unroll
    for (int r = 0; r < 16; ++r) {
        const int k = r*256 + tid;
        const float t = vs2[k];
        p2l += t*t;
        const int g = k >> 6, cc = k & 63;
        apl += out[OFF_ADJ + (size_t)g*4096 + cc*65];   // diagonal entries
    }
    float a2l = a2p[tid];
#pragma unroll
    for (int off = 32; off > 0; off >>= 1) {
        p2l += __shfl_down(p2l, off);
        apl += __shfl_down(apl, off);
        a2l += __shfl_down(a2l, off);
    }
    __shared__ float red[3][4];
    if ((tid & 63) == 0) {
        red[0][tid>>6] = p2l; red[1][tid>>6] = apl; red[2][tid>>6] = a2l;
    }
    __syncthreads();
    if (tid == 0) {
        const float p2 = red[0][0]+red[0][1]+red[0][2]+red[0][3];
        const float ap = red[1][0]+red[1][1]+red[1][2]+red[1][3];
        const float a2 = red[2][0]+red[2][1]+red[2][2]+red[2][3];
        const float val = a2 - 2.0f*ap + p2;
        out[OFF_LL] = sqrtf(fmaxf(val, 0.f)) / (float)kE;
        out[OFF_Z]  = 0.0f;
    }
}

// ----------------------------------------------------------------- launch
extern "C" void kernel_launch(void* const* d_in, const int* in_sizes, int n_in,
                              void* d_out, int out_size, void* d_ws, size_t ws_size,
                              hipStream_t stream)
{
    const float* x  = (const float*)d_in[0];
    const int*   ei = (const int*)d_in[1];
    const float* ew = (const float*)d_in[2];
    const float* Wm = (const float*)d_in[5];
    const float* bv = (const float*)d_in[6];
    float* out = (float*)d_out;
    char*  ws  = (char*)d_ws;
    int*   carr  = (int*)(ws + WS_C);
    float* varr  = (float*)(ws + WS_V);
    float* vs2   = (float*)(ws + WS_VS2);
    float* a2p   = (float*)(ws + WS_A2);
    int*   perm  = (int*)(ws + WS_PERM);
    int*   strt  = (int*)(ws + WS_STRT);
    float* padj  = (float*)(ws + WS_PADJ);

    k_const    <<<2065, 256, 0, stream>>>(out);
    k_logits   <<<512,  256, 0, stream>>>(x, Wm, bv, carr, varr);
    k_sort     <<<64,  1024, 0, stream>>>(carr, perm, strt);
    k_pool_x   <<<512, 1024, 0, stream>>>(x, perm, strt, varr, out, vs2);
    k_adj      <<<256, 1024, 0, stream>>>(ei, ew, carr, varr, padj, a2p);
    k_adj_merge<<<1024, 256, 0, stream>>>(padj, out);
    k_final    <<<1,    256, 0, stream>>>(vs2, a2p, out);
}